// Round 6
// baseline (512.465 us; speedup 1.0000x reference)
//
#include <hip/hip_runtime.h>
#include <hip/hip_bf16.h>

#define B_ 16
#define N_ 4096
#define S_ 1024
#define K_ 32
#define D_ 64
#define M_ (B_*S_*K_)            // 524288 rows
#define EPS_ 1e-5f

#define OUT_NRM  (B_*S_*3)       // 49152
#define OUT_FEAT (2*B_*S_*3)     // 98304
#define OUT_FPS  (OUT_FEAT + B_*S_*128)  // 2195456

typedef __attribute__((ext_vector_type(8))) short bf16x8;
typedef __attribute__((ext_vector_type(4))) float f32x4;

__device__ __forceinline__ unsigned short rnb(float x){
  return (unsigned short)((__float_as_uint(x) + 0x8000u) >> 16);
}
__device__ __forceinline__ void split1(float x, short& h, short& l){
  unsigned ux = __float_as_uint(x);
  unsigned uh = (ux + 0x8000u) & 0xFFFF0000u;
  h = (short)(uh >> 16);
  float lo = x - __uint_as_float(uh);
  l = (short)((__float_as_uint(lo) + 0x8000u) >> 16);
}

// reduce 4 values across 16 lr-lanes; lane with bits(3,2)=(b3,b2) holds total of v[2*b3+b2]
__device__ __forceinline__ float hred4_sum(const float v[4], int l){
  bool hi8 = (l & 8) != 0;
  float send0 = hi8 ? v[0] : v[2];
  float send1 = hi8 ? v[1] : v[3];
  float r0 = __shfl_xor(send0, 8);
  float r1 = __shfl_xor(send1, 8);
  float a0 = (hi8 ? v[2] : v[0]) + r0;
  float a1 = (hi8 ? v[3] : v[1]) + r1;
  bool hi4 = (l & 4) != 0;
  float send = hi4 ? a0 : a1;
  float r = __shfl_xor(send, 4);
  float a = (hi4 ? a1 : a0) + r;
  a += __shfl_xor(a, 2);
  a += __shfl_xor(a, 1);
  return a;
}
__device__ __forceinline__ float hred4_max(const float v[4], int l){
  bool hi8 = (l & 8) != 0;
  float send0 = hi8 ? v[0] : v[2];
  float send1 = hi8 ? v[1] : v[3];
  float r0 = __shfl_xor(send0, 8);
  float r1 = __shfl_xor(send1, 8);
  float a0 = fmaxf(hi8 ? v[2] : v[0], r0);
  float a1 = fmaxf(hi8 ? v[3] : v[1], r1);
  bool hi4 = (l & 4) != 0;
  float send = hi4 ? a0 : a1;
  float r = __shfl_xor(send, 4);
  float a = fmaxf(hi4 ? a1 : a0, r);
  a = fmaxf(a, __shfl_xor(a, 2));
  a = fmaxf(a, __shfl_xor(a, 1));
  return a;
}

// stats: 8 replicas x 512 floats (S1@0 Q1@64 S2@128 Q2@192 S3@256(128) Q3@384(128))
__global__ void zero_stats_kernel(float* __restrict__ stats){
  int t = blockIdx.x*256 + threadIdx.x;
  stats[t] = 0.f;    // grid covers 4096 floats
}

__global__ void meta_kernel(const float* __restrict__ xyz, const float* __restrict__ nrm,
                            const int* __restrict__ fps, float* __restrict__ out){
  int t = blockIdx.x*256 + threadIdx.x;
  if (t >= B_*S_) return;
  int b = t >> 10;
  int n = fps[t];
  const float* xp = xyz + ((size_t)b*N_ + n)*3;
  out[t*3+0] = xp[0]; out[t*3+1] = xp[1]; out[t*3+2] = xp[2];
  const float* pp = nrm + ((size_t)b*N_ + n)*3;
  out[OUT_NRM + t*3+0] = pp[0]; out[OUT_NRM + t*3+1] = pp[1]; out[OUT_NRM + t*3+2] = pp[2];
  out[OUT_FPS + t] = (float)n;
}

__global__ void prepack_kernel(const float* __restrict__ xyz, float4* __restrict__ packed){
  int t = blockIdx.x*256 + threadIdx.x;
  if (t >= B_*N_) return;
  float x = xyz[t*3+0], y = xyz[t*3+1], z = xyz[t*3+2];
  float pp = __fadd_rn(__fadd_rn(__fmul_rn(x,x), __fmul_rn(y,y)), __fmul_rn(z,z));
  packed[t] = make_float4(x, y, z, pp);
}

// pack W into per-lane MFMA A-fragments (bf16). w0 [0,4096) w1 [4096,8192) w2 [8192,16384)
__global__ void packw_kernel(const float* __restrict__ w0, const float* __restrict__ w1,
                             const float* __restrict__ w2, unsigned short* __restrict__ dst){
  int e = blockIdx.x*256 + threadIdx.x;
  if (e >= 16384) return;
  const float* W; int base;
  if (e < 4096){ W = w0; base = 0; }
  else if (e < 8192){ W = w1; base = 4096; }
  else { W = w2; base = 8192; }
  int r = e - base;
  int frag = r >> 9;          // (cht*2 + ks)
  int lane = (r >> 3) & 63;
  int j = r & 7;
  int cht = frag >> 1, ks = frag & 1;
  int m = lane & 15, quad = lane >> 4;
  int ch = cht*16 + m, k = ks*32 + quad*8 + j;
  dst[e] = rnb(W[ch*64 + k]);
}

// ---- KNN: one wave/query, no key array (recompute), LDS-atomic compaction ----
__global__ __launch_bounds__(256, 8) void knn_kernel(const float4* __restrict__ packed,
                                                     const int* __restrict__ fps,
                                                     int* __restrict__ idxout){
  __shared__ unsigned skey[4][64];
  __shared__ int      sidx[4][64];
  __shared__ unsigned scnt[4];
  const int w = threadIdx.x >> 6;
  const int l = threadIdx.x & 63;
  const int q = blockIdx.x*4 + w;
  const int b = q >> 10;
  const float4* pb = packed + (size_t)b*N_;
  const int nq = fps[q];
  const float4 qp = pb[nq];
  const float qx = qp.x, qy = qp.y, qz = qp.z, qq = qp.w;

  // pass A: running float min only (no storage)
  float vmin = 3.0e38f;
  #pragma unroll 8
  for (int i = 0; i < 64; i++){
    float4 p = pb[i*64 + l];
    float dt = __fadd_rn(__fadd_rn(__fmul_rn(qx,p.x), __fmul_rn(qy,p.y)), __fmul_rn(qz,p.z));
    float d  = __fsub_rn(__fadd_rn(qq,p.w), __fmul_rn(2.f,dt));
    vmin = fminf(vmin, d);
  }
  // bitonic sort the 64 lane-minima (floats); rank-31 bounds the global 32nd-smallest
  {
    float v = vmin;
    #pragma unroll
    for (int k = 2; k <= 64; k <<= 1){
      #pragma unroll
      for (int j = k >> 1; j > 0; j >>= 1){
        float o = __shfl_xor(v, j);
        bool keepmin = (((l & k) == 0)) ^ ((l & j) != 0);
        v = keepmin ? fminf(v, o) : fmaxf(v, o);
      }
    }
    vmin = v;
  }
  const float T = __shfl(vmin, 31);

  // init compaction buffers (same-wave LDS, no barrier)
  skey[w][l] = 0xFFFFFFFFu;
  sidx[w][l] = 0x7FFFFFFF;
  if (l == 0) scnt[w] = 0;

  // pass B: recompute, compact survivors via LDS atomic counter (order-free:
  // the total-order sort below makes the result deterministic)
  #pragma unroll 4
  for (int i = 0; i < 64; i++){
    float4 p = pb[i*64 + l];
    float dt = __fadd_rn(__fadd_rn(__fmul_rn(qx,p.x), __fmul_rn(qy,p.y)), __fmul_rn(qz,p.z));
    float d  = __fsub_rn(__fadd_rn(qq,p.w), __fmul_rn(2.f,dt));
    if (d <= T){
      unsigned pos = atomicAdd(&scnt[w], 1u);
      if (pos < 64){
        unsigned u = __float_as_uint(d);
        u ^= (unsigned)(((int)u >> 31)) | 0x80000000u;
        skey[w][pos] = u;
        sidx[w][pos] = i*64 + l;
      }
    }
  }
  const unsigned total = scnt[w];   // >= 32 guaranteed

  const size_t obase = (size_t)q * K_;
  if (total <= 64){
    unsigned long long sk = ((unsigned long long)skey[w][l] << 32) | (unsigned)sidx[w][l];
    // bitonic sort 64 (key,idx) ascending -> lanes 0..31 hold exact top-32 (ref tie-break)
    #pragma unroll
    for (int k = 2; k <= 64; k <<= 1){
      #pragma unroll
      for (int j = k >> 1; j > 0; j >>= 1){
        unsigned long long o = __shfl_xor(sk, j);
        bool keepmin = (((l & k) == 0)) ^ ((l & j) != 0);
        unsigned long long mn = (sk < o) ? sk : o;
        unsigned long long mx = (sk < o) ? o : sk;
        sk = keepmin ? mn : mx;
      }
    }
    if (l < 32) idxout[obase + l] = (int)(unsigned)(sk & 0xFFFFFFFFull);
  } else {
    // rare exact fallback: bisection on 44-bit (key, idx), keys recomputed
    unsigned long long lo = 0, hi = (1ull << 44) - 1;
    for (int it = 0; it < 44; ++it){
      unsigned long long mid = (lo + hi) >> 1;
      unsigned midk = (unsigned)(mid >> 12);
      unsigned midi = (unsigned)(mid & 0xFFFull);
      int cc = 0;
      for (int i = 0; i < 64; i++){
        float4 p = pb[i*64 + l];
        float dt = __fadd_rn(__fadd_rn(__fmul_rn(qx,p.x), __fmul_rn(qy,p.y)), __fmul_rn(qz,p.z));
        float d  = __fsub_rn(__fadd_rn(qq,p.w), __fmul_rn(2.f,dt));
        unsigned u = __float_as_uint(d);
        u ^= (unsigned)(((int)u >> 31)) | 0x80000000u;
        unsigned n = (unsigned)(i*64 + l);
        cc += (u < midk || (u == midk && n <= midi)) ? 1 : 0;
      }
      #pragma unroll
      for (int o2 = 32; o2 > 0; o2 >>= 1) cc += __shfl_xor(cc, o2);
      if (cc >= 32) hi = mid; else lo = mid + 1;
    }
    const unsigned Ck = (unsigned)(lo >> 12);
    const unsigned Ci = (unsigned)(lo & 0xFFFull);
    if (l == 0) scnt[w] = 0;
    for (int i = 0; i < 64; i++){
      float4 p = pb[i*64 + l];
      float dt = __fadd_rn(__fadd_rn(__fmul_rn(qx,p.x), __fmul_rn(qy,p.y)), __fmul_rn(qz,p.z));
      float d  = __fsub_rn(__fadd_rn(qq,p.w), __fmul_rn(2.f,dt));
      unsigned u = __float_as_uint(d);
      u ^= (unsigned)(((int)u >> 31)) | 0x80000000u;
      unsigned n = (unsigned)(i*64 + l);
      if (u < Ck || (u == Ck && n <= Ci)){
        unsigned pos = atomicAdd(&scnt[w], 1u);
        skey[w][pos] = u;
        sidx[w][pos] = (int)n;
      }
    }
    // exactly 32 selected; sort them for determinism via same 64-wide network
    unsigned mykey = (l < 32) ? skey[w][l] : 0xFFFFFFFFu;
    unsigned myidx = (l < 32) ? (unsigned)sidx[w][l] : 0xFFFFFFFFu;
    unsigned long long sk = ((unsigned long long)mykey << 32) | myidx;
    #pragma unroll
    for (int k = 2; k <= 64; k <<= 1){
      #pragma unroll
      for (int j = k >> 1; j > 0; j >>= 1){
        unsigned long long o = __shfl_xor(sk, j);
        bool keepmin = (((l & k) == 0)) ^ ((l & j) != 0);
        unsigned long long mn = (sk < o) ? sk : o;
        unsigned long long mx = (sk < o) ? o : sk;
        sk = keepmin ? mn : mx;
      }
    }
    if (l < 32) idxout[obase + l] = (int)(unsigned)(sk & 0xFFFFFFFFull);
  }
}

// ---- conv1: gather -> split-MFMA -> Y1 + stats. 64 rows/wave, grid 2048 ----
__global__ __launch_bounds__(256, 2) void conv1_mfma(const float* __restrict__ pts,
    const int* __restrict__ idx, const unsigned short* __restrict__ wpk,
    const float* __restrict__ bias, unsigned short* __restrict__ Yo,
    float* __restrict__ stats){
  __shared__ float sred[4][128];
  const int t = threadIdx.x, w = t>>6, l = t&63, quad = l>>4, lr = l&15;
  const int m0 = blockIdx.x*256;
  const int Rw = m0 + w*64;
  const int b = m0 >> 15;
  bf16x8 wf[4][2];
  #pragma unroll
  for (int c = 0; c < 4; c++)
    #pragma unroll
    for (int s = 0; s < 2; s++)
      wf[c][s] = *(const bf16x8*)(wpk + (((c*2+s)<<6) + l)*8);
  f32x4 acc[4][4];
  #pragma unroll
  for (int c = 0; c < 4; c++)
    #pragma unroll
    for (int rt = 0; rt < 4; rt++)
      acc[c][rt] = (f32x4){0.f,0.f,0.f,0.f};
  int ri[4];
  #pragma unroll
  for (int rt = 0; rt < 4; rt++) ri[rt] = idx[Rw + rt*16 + lr];
  #pragma unroll
  for (int s = 0; s < 2; s++){
    #pragma unroll
    for (int rt = 0; rt < 4; rt++){
      const float* pr = pts + ((size_t)(b*4096 + ri[rt]))*64;
      float4 v0 = *(const float4*)(pr + s*32 + quad*8);
      float4 v1 = *(const float4*)(pr + s*32 + quad*8 + 4);
      float xs[8] = {v0.x,v0.y,v0.z,v0.w,v1.x,v1.y,v1.z,v1.w};
      bf16x8 xh, xl;
      #pragma unroll
      for (int j = 0; j < 8; j++){ short hh, ll; split1(xs[j], hh, ll); xh[j]=hh; xl[j]=ll; }
      #pragma unroll
      for (int c = 0; c < 4; c++){
        acc[c][rt] = __builtin_amdgcn_mfma_f32_16x16x32_bf16(wf[c][s], xh, acc[c][rt], 0,0,0);
        acc[c][rt] = __builtin_amdgcn_mfma_f32_16x16x32_bf16(wf[c][s], xl, acc[c][rt], 0,0,0);
      }
    }
  }
  const int rtg0 = Rw >> 4;
  #pragma unroll
  for (int c = 0; c < 4; c++){
    float4 bq = *(const float4*)(bias + c*16 + quad*4);
    float bqa[4] = {bq.x, bq.y, bq.z, bq.w};
    float sv[4] = {0,0,0,0}, qv[4] = {0,0,0,0};
    int kb = c*2 + (quad>>1);
    int sub = (quad&1)*4;
    #pragma unroll
    for (int rt = 0; rt < 4; rt++){
      float y[4];
      #pragma unroll
      for (int r = 0; r < 4; r++){
        y[r] = acc[c][rt][r] + bqa[r];
        sv[r] += y[r];
        qv[r] += y[r]*y[r];
      }
      uint2 p;
      p.x = (unsigned)rnb(y[0]) | ((unsigned)rnb(y[1])<<16);
      p.y = (unsigned)rnb(y[2]) | ((unsigned)rnb(y[3])<<16);
      *(uint2*)(Yo + ((((rtg0+rt)*8 + kb)*16 + lr)*8 + sub)) = p;
    }
    float S = hred4_sum(sv, l);
    float Q = hred4_sum(qv, l);
    if ((l & 3) == 0){
      int ch = c*16 + quad*4 + ((l>>3)&1)*2 + ((l>>2)&1);
      sred[w][ch] = S;
      sred[w][64 + ch] = Q;
    }
  }
  __syncthreads();
  if (t < 128){
    float tot = sred[0][t]+sred[1][t]+sred[2][t]+sred[3][t];
    unsafeAtomicAdd(&stats[(blockIdx.x & 7)*512 + t], tot);
  }
}

// ---- conv2: Y1 -> affine+relu -> MFMA (no split) -> Y2 + stats. 64 rows/wave ----
__global__ __launch_bounds__(256, 2) void conv2_mfma(const unsigned short* __restrict__ Yi,
    const unsigned short* __restrict__ wpk, const float* __restrict__ bias,
    const float* __restrict__ aff, unsigned short* __restrict__ Yo,
    float* __restrict__ stats){
  __shared__ float sred[4][128];
  const int t = threadIdx.x, w = t>>6, l = t&63, quad = l>>4, lr = l&15;
  const int m0 = blockIdx.x*256;
  const int Rw = m0 + w*64;
  bf16x8 wf[4][2];
  #pragma unroll
  for (int c = 0; c < 4; c++)
    #pragma unroll
    for (int s = 0; s < 2; s++)
      wf[c][s] = *(const bf16x8*)(wpk + (((c*2+s)<<6) + l)*8);
  f32x4 acc[4][4];
  #pragma unroll
  for (int c = 0; c < 4; c++)
    #pragma unroll
    for (int rt = 0; rt < 4; rt++)
      acc[c][rt] = (f32x4){0.f,0.f,0.f,0.f};
  const int rtg0 = Rw >> 4;
  #pragma unroll
  for (int s = 0; s < 2; s++){
    float4 A0 = *(const float4*)(aff + s*32 + quad*8);
    float4 A1 = *(const float4*)(aff + s*32 + quad*8 + 4);
    float4 B0 = *(const float4*)(aff + 64 + s*32 + quad*8);
    float4 B1 = *(const float4*)(aff + 64 + s*32 + quad*8 + 4);
    float aA[8] = {A0.x,A0.y,A0.z,A0.w,A1.x,A1.y,A1.z,A1.w};
    float aB[8] = {B0.x,B0.y,B0.z,B0.w,B1.x,B1.y,B1.z,B1.w};
    #pragma unroll
    for (int rt = 0; rt < 4; rt++){
      uint4 u = *(const uint4*)(Yi + (((rtg0+rt)*8 + s*4 + quad)*16 + lr)*8);
      unsigned ua[4] = {u.x,u.y,u.z,u.w};
      bf16x8 xb;
      #pragma unroll
      for (int j = 0; j < 8; j++){
        unsigned wd = ua[j>>1];
        float yf = __uint_as_float((j&1) ? (wd & 0xFFFF0000u) : (wd << 16));
        float x = fmaxf(0.f, fmaf(yf, aA[j], aB[j]));
        xb[j] = (short)rnb(x);
      }
      #pragma unroll
      for (int c = 0; c < 4; c++)
        acc[c][rt] = __builtin_amdgcn_mfma_f32_16x16x32_bf16(wf[c][s], xb, acc[c][rt], 0,0,0);
    }
  }
  #pragma unroll
  for (int c = 0; c < 4; c++){
    float4 bq = *(const float4*)(bias + c*16 + quad*4);
    float bqa[4] = {bq.x, bq.y, bq.z, bq.w};
    float sv[4] = {0,0,0,0}, qv[4] = {0,0,0,0};
    int kb = c*2 + (quad>>1);
    int sub = (quad&1)*4;
    #pragma unroll
    for (int rt = 0; rt < 4; rt++){
      float y[4];
      #pragma unroll
      for (int r = 0; r < 4; r++){
        y[r] = acc[c][rt][r] + bqa[r];
        sv[r] += y[r];
        qv[r] += y[r]*y[r];
      }
      uint2 p;
      p.x = (unsigned)rnb(y[0]) | ((unsigned)rnb(y[1])<<16);
      p.y = (unsigned)rnb(y[2]) | ((unsigned)rnb(y[3])<<16);
      *(uint2*)(Yo + ((((rtg0+rt)*8 + kb)*16 + lr)*8 + sub)) = p;
    }
    float S = hred4_sum(sv, l);
    float Q = hred4_sum(qv, l);
    if ((l & 3) == 0){
      int ch = c*16 + quad*4 + ((l>>3)&1)*2 + ((l>>2)&1);
      sred[w][ch] = S;
      sred[w][64 + ch] = Q;
    }
  }
  __syncthreads();
  if (t < 128){
    float tot = sred[0][t]+sred[1][t]+sred[2][t]+sred[3][t];
    unsafeAtomicAdd(&stats[(blockIdx.x & 7)*512 + 128 + t], tot);
  }
}

// ---- conv3: Y2 -> affine+relu -> MFMA (no split) -> K-maxpool + stats. 32 rows/wave ----
__global__ __launch_bounds__(256, 2) void conv3_mfma(const unsigned short* __restrict__ Yi,
    const unsigned short* __restrict__ wpk, const float* __restrict__ bias,
    const float* __restrict__ aff, float* __restrict__ ymax,
    float* __restrict__ stats){
  __shared__ float sred[4][256];
  const int t = threadIdx.x, w = t>>6, l = t&63, quad = l>>4, lr = l&15;
  const int m0 = blockIdx.x*128;
  const int Rw = m0 + w*32;
  bf16x8 wf[8][2];
  #pragma unroll
  for (int c = 0; c < 8; c++)
    #pragma unroll
    for (int s = 0; s < 2; s++)
      wf[c][s] = *(const bf16x8*)(wpk + (((c*2+s)<<6) + l)*8);
  f32x4 acc[8][2];
  #pragma unroll
  for (int c = 0; c < 8; c++){
    acc[c][0] = (f32x4){0.f,0.f,0.f,0.f};
    acc[c][1] = (f32x4){0.f,0.f,0.f,0.f};
  }
  const int rtg0 = Rw >> 4;
  #pragma unroll
  for (int s = 0; s < 2; s++){
    float4 A0 = *(const float4*)(aff + s*32 + quad*8);
    float4 A1 = *(const float4*)(aff + s*32 + quad*8 + 4);
    float4 B0 = *(const float4*)(aff + 64 + s*32 + quad*8);
    float4 B1 = *(const float4*)(aff + 64 + s*32 + quad*8 + 4);
    float aA[8] = {A0.x,A0.y,A0.z,A0.w,A1.x,A1.y,A1.z,A1.w};
    float aB[8] = {B0.x,B0.y,B0.z,B0.w,B1.x,B1.y,B1.z,B1.w};
    #pragma unroll
    for (int rt = 0; rt < 2; rt++){
      uint4 u = *(const uint4*)(Yi + (((rtg0+rt)*8 + s*4 + quad)*16 + lr)*8);
      unsigned ua[4] = {u.x,u.y,u.z,u.w};
      bf16x8 xb;
      #pragma unroll
      for (int j = 0; j < 8; j++){
        unsigned wd = ua[j>>1];
        float yf = __uint_as_float((j&1) ? (wd & 0xFFFF0000u) : (wd << 16));
        float x = fmaxf(0.f, fmaf(yf, aA[j], aB[j]));
        xb[j] = (short)rnb(x);
      }
      #pragma unroll
      for (int c = 0; c < 8; c++)
        acc[c][rt] = __builtin_amdgcn_mfma_f32_16x16x32_bf16(wf[c][s], xb, acc[c][rt], 0,0,0);
    }
  }
  const int g = Rw >> 5;       // group = b*S + s (wave = one K=32 group)
  #pragma unroll
  for (int c = 0; c < 8; c++){
    float4 bq = *(const float4*)(bias + c*16 + quad*4);
    float bqa[4] = {bq.x, bq.y, bq.z, bq.w};
    float sv[4], qv[4], mv[4];
    #pragma unroll
    for (int r = 0; r < 4; r++){
      float y0 = acc[c][0][r] + bqa[r];
      float y1 = acc[c][1][r] + bqa[r];
      sv[r] = y0 + y1;
      qv[r] = y0*y0 + y1*y1;
      mv[r] = fmaxf(y0, y1);
    }
    float S = hred4_sum(sv, l);
    float Q = hred4_sum(qv, l);
    float Mx = hred4_max(mv, l);
    if ((l & 3) == 0){
      int ch = c*16 + quad*4 + ((l>>3)&1)*2 + ((l>>2)&1);
      sred[w][ch] = S;
      sred[w][128 + ch] = Q;
      ymax[(size_t)g*128 + ch] = Mx;
    }
  }
  __syncthreads();
  {
    float tot = sred[0][t]+sred[1][t]+sred[2][t]+sred[3][t];
    unsafeAtomicAdd(&stats[(blockIdx.x & 7)*512 + 256 + t], tot);
  }
}

__global__ void bnparam_kernel(const float* __restrict__ stats, const float* __restrict__ g,
                               const float* __restrict__ bt, float* __restrict__ outAS,
                               int sOff, int qOff, int C){
  int c = threadIdx.x;
  if (c >= C) return;
  const float inv = 1.f/(float)M_;
  float S = 0.f, Q = 0.f;
  #pragma unroll
  for (int r = 0; r < 8; r++){
    S += stats[r*512 + sOff + c];
    Q += stats[r*512 + qOff + c];
  }
  float mean = S * inv;
  float var  = Q * inv - mean*mean;
  float a = g[c] * rsqrtf(var + EPS_);
  outAS[c] = a;
  outAS[C + c] = bt[c] - mean*a;
}

__global__ void final_kernel(const float* __restrict__ ymax,
                             const float* __restrict__ affb, float* __restrict__ out){
  int t = blockIdx.x*256 + threadIdx.x;     // (b*S+s)*128 + o
  int o = t & 127;
  float a = affb[256 + o], s = affb[384 + o];
  // g=ones => a = rsqrt(var+eps) > 0, so max commutes with the affine+relu
  out[OUT_FEAT + t] = fmaxf(0.f, a*ymax[t] + s);
}

extern "C" void kernel_launch(void* const* d_in, const int* in_sizes, int n_in,
                              void* d_out, int out_size, void* d_ws, size_t ws_size,
                              hipStream_t stream) {
  const float* xyz = (const float*)d_in[0];
  const float* nrm = (const float*)d_in[1];
  const float* pts = (const float*)d_in[2];
  const int*   fps = (const int*)d_in[3];
  const float* w0  = (const float*)d_in[4];
  const float* b0  = (const float*)d_in[5];
  const float* g0  = (const float*)d_in[6];
  const float* bt0 = (const float*)d_in[7];
  const float* w1  = (const float*)d_in[8];
  const float* b1  = (const float*)d_in[9];
  const float* g1  = (const float*)d_in[10];
  const float* bt1 = (const float*)d_in[11];
  const float* w2  = (const float*)d_in[12];
  const float* b2  = (const float*)d_in[13];
  const float* g2  = (const float*)d_in[14];
  const float* bt2 = (const float*)d_in[15];
  float* out = (float*)d_out;

  char* ws = (char*)d_ws;
  float* stats = (float*)ws;                                  // 16 KB (8 replicas x 512 f)
  float* affb  = (float*)(ws + 16384);                        // 2 KB aff params
  int*   idxb  = (int*)(ws + 20480);                          // 2 MB
  float* ymax  = (float*)(ws + 2117632);                      // 8 MB
  float4* packed = (float4*)(ws + 10506240);                  // 1 MB
  unsigned short* wpack = (unsigned short*)(ws + 11554816);   // 32 KB
  unsigned short* Y1 = (unsigned short*)(ws + 18878464);      // 64 MB
  unsigned short* Y2 = (unsigned short*)(ws + 85987328);      // 64 MB (ends 153096192)

  zero_stats_kernel<<<16, 256, 0, stream>>>(stats);
  meta_kernel<<<64, 256, 0, stream>>>(xyz, nrm, fps, out);
  prepack_kernel<<<256, 256, 0, stream>>>(xyz, packed);
  packw_kernel<<<64, 256, 0, stream>>>(w0, w1, w2, wpack);
  knn_kernel<<<4096, 256, 0, stream>>>(packed, fps, idxb);
  conv1_mfma<<<2048, 256, 0, stream>>>(pts, idxb, wpack, b0, Y1, stats);
  bnparam_kernel<<<1, 64, 0, stream>>>(stats, g0, bt0, affb, 0, 64, 64);
  conv2_mfma<<<2048, 256, 0, stream>>>(Y1, wpack + 4096, b1, affb, Y2, stats);
  bnparam_kernel<<<1, 64, 0, stream>>>(stats, g1, bt1, affb + 128, 128, 192, 64);
  conv3_mfma<<<4096, 256, 0, stream>>>(Y2, wpack + 8192, b2, affb + 128, ymax, stats);
  bnparam_kernel<<<1, 128, 0, stream>>>(stats, g2, bt2, affb + 256, 256, 384, 128);
  final_kernel<<<8192, 256, 0, stream>>>(ymax, affb, out);
}

// Round 7
// 300.246 us; speedup vs baseline: 1.7068x; 1.7068x over previous
//
#include <hip/hip_runtime.h>
#include <hip/hip_bf16.h>

#define B_ 16
#define N_ 4096
#define S_ 1024
#define K_ 32
#define D_ 64
#define M_ (B_*S_*K_)            // 524288 rows
#define EPS_ 1e-5f

#define OUT_NRM  (B_*S_*3)       // 49152
#define OUT_FEAT (2*B_*S_*3)     // 98304
#define OUT_FPS  (OUT_FEAT + B_*S_*128)  // 2195456

typedef __attribute__((ext_vector_type(8))) short bf16x8;
typedef __attribute__((ext_vector_type(4))) float f32x4;

__device__ __forceinline__ unsigned short rnb(float x){
  return (unsigned short)((__float_as_uint(x) + 0x8000u) >> 16);
}
__device__ __forceinline__ void split1(float x, short& h, short& l){
  unsigned ux = __float_as_uint(x);
  unsigned uh = (ux + 0x8000u) & 0xFFFF0000u;
  h = (short)(uh >> 16);
  float lo = x - __uint_as_float(uh);
  l = (short)((__float_as_uint(lo) + 0x8000u) >> 16);
}

// reduce 4 values across 16 lr-lanes; lane with bits(3,2)=(b3,b2) holds total of v[2*b3+b2]
__device__ __forceinline__ float hred4_sum(const float v[4], int l){
  bool hi8 = (l & 8) != 0;
  float send0 = hi8 ? v[0] : v[2];
  float send1 = hi8 ? v[1] : v[3];
  float r0 = __shfl_xor(send0, 8);
  float r1 = __shfl_xor(send1, 8);
  float a0 = (hi8 ? v[2] : v[0]) + r0;
  float a1 = (hi8 ? v[3] : v[1]) + r1;
  bool hi4 = (l & 4) != 0;
  float send = hi4 ? a0 : a1;
  float r = __shfl_xor(send, 4);
  float a = (hi4 ? a1 : a0) + r;
  a += __shfl_xor(a, 2);
  a += __shfl_xor(a, 1);
  return a;
}
__device__ __forceinline__ float hred4_max(const float v[4], int l){
  bool hi8 = (l & 8) != 0;
  float send0 = hi8 ? v[0] : v[2];
  float send1 = hi8 ? v[1] : v[3];
  float r0 = __shfl_xor(send0, 8);
  float r1 = __shfl_xor(send1, 8);
  float a0 = fmaxf(hi8 ? v[2] : v[0], r0);
  float a1 = fmaxf(hi8 ? v[3] : v[1], r1);
  bool hi4 = (l & 4) != 0;
  float send = hi4 ? a0 : a1;
  float r = __shfl_xor(send, 4);
  float a = fmaxf(hi4 ? a1 : a0, r);
  a = fmaxf(a, __shfl_xor(a, 2));
  a = fmaxf(a, __shfl_xor(a, 1));
  return a;
}

// stats: 8 replicas x 512 floats (S1@0 Q1@64 S2@128 Q2@192 S3@256(128) Q3@384(128))
__global__ void zero_stats_kernel(float* __restrict__ stats){
  int t = blockIdx.x*256 + threadIdx.x;
  stats[t] = 0.f;    // grid covers 4096 floats
}

__global__ void meta_kernel(const float* __restrict__ xyz, const float* __restrict__ nrm,
                            const int* __restrict__ fps, float* __restrict__ out){
  int t = blockIdx.x*256 + threadIdx.x;
  if (t >= B_*S_) return;
  int b = t >> 10;
  int n = fps[t];
  const float* xp = xyz + ((size_t)b*N_ + n)*3;
  out[t*3+0] = xp[0]; out[t*3+1] = xp[1]; out[t*3+2] = xp[2];
  const float* pp = nrm + ((size_t)b*N_ + n)*3;
  out[OUT_NRM + t*3+0] = pp[0]; out[OUT_NRM + t*3+1] = pp[1]; out[OUT_NRM + t*3+2] = pp[2];
  out[OUT_FPS + t] = (float)n;
}

// pack W into per-lane MFMA A-fragments (bf16). w0 [0,4096) w1 [4096,8192) w2 [8192,16384)
__global__ void packw_kernel(const float* __restrict__ w0, const float* __restrict__ w1,
                             const float* __restrict__ w2, unsigned short* __restrict__ dst){
  int e = blockIdx.x*256 + threadIdx.x;
  if (e >= 16384) return;
  const float* W; int base;
  if (e < 4096){ W = w0; base = 0; }
  else if (e < 8192){ W = w1; base = 4096; }
  else { W = w2; base = 8192; }
  int r = e - base;
  int frag = r >> 9;          // (cht*2 + ks)
  int lane = (r >> 3) & 63;
  int j = r & 7;
  int cht = frag >> 1, ks = frag & 1;
  int m = lane & 15, quad = lane >> 4;
  int ch = cht*16 + m, k = ks*32 + quad*8 + j;
  dst[e] = rnb(W[ch*64 + k]);
}

// ---- KNN: LDS-staged batch xyz; 16 queries/block (4/wave); dv[64] in regs ----
__global__ __launch_bounds__(256, 2) void knn_kernel(const float* __restrict__ xyz,
                                                     const int* __restrict__ fps,
                                                     int* __restrict__ idxout){
  __shared__ float Lx[N_*3];         // 48 KB: this batch's xyz
  __shared__ unsigned skey[4][64];   // per-wave compaction scratch
  __shared__ int      sidx[4][64];
  const int t = threadIdx.x;
  const int w = t >> 6, l = t & 63;
  const int b = blockIdx.x >> 6;     // 64 blocks per batch
  {
    const float4* src = (const float4*)(xyz + (size_t)b*(N_*3));
    float4* dst = (float4*)Lx;
    #pragma unroll
    for (int j = 0; j < 12; j++) dst[j*256 + t] = src[j*256 + t];
  }
  __syncthreads();
  const int q0 = blockIdx.x*16 + w*4;
  for (int sq = 0; sq < 4; sq++){
    const int q = q0 + sq;
    const int nq = fps[q];
    const float qx = Lx[nq*3], qy = Lx[nq*3+1], qz = Lx[nq*3+2];
    const float qq = __fadd_rn(__fadd_rn(__fmul_rn(qx,qx), __fmul_rn(qy,qy)), __fmul_rn(qz,qz));
    float dv[64];
    float vmin = 3.0e38f;
    #pragma unroll
    for (int i = 0; i < 64; i++){
      const float* p = &Lx[(i*64 + l)*3];
      float px = p[0], py = p[1], pz = p[2];
      float pp = __fadd_rn(__fadd_rn(__fmul_rn(px,px), __fmul_rn(py,py)), __fmul_rn(pz,pz));
      float dt = __fadd_rn(__fadd_rn(__fmul_rn(qx,px), __fmul_rn(qy,py)), __fmul_rn(qz,pz));
      float d  = __fsub_rn(__fadd_rn(qq,pp), __fmul_rn(2.f,dt));
      dv[i] = d;
      vmin = fminf(vmin, d);
    }
    // bitonic sort the 64 lane-minima; rank-31 bounds the global 32nd-smallest
    {
      float v = vmin;
      #pragma unroll
      for (int k = 2; k <= 64; k <<= 1){
        #pragma unroll
        for (int j = k >> 1; j > 0; j >>= 1){
          float o = __shfl_xor(v, j);
          bool keepmin = (((l & k) == 0)) ^ ((l & j) != 0);
          v = keepmin ? fminf(v, o) : fmaxf(v, o);
        }
      }
      vmin = v;
    }
    const float T = __shfl(vmin, 31);
    int c = 0;
    #pragma unroll
    for (int i = 0; i < 64; i++) c += (dv[i] <= T) ? 1 : 0;
    int inc = c;
    #pragma unroll
    for (int off = 1; off < 64; off <<= 1){
      int t2 = __shfl_up(inc, off);
      if (l >= off) inc += t2;
    }
    const int excl = inc - c;
    const int total = __shfl(inc, 63);   // >= 32 guaranteed
    const size_t obase = (size_t)q * K_;
    skey[w][l] = 0xFFFFFFFFu;
    sidx[w][l] = 0x7FFFFFFF;
    if (total <= 64){
      int off2 = excl;
      #pragma unroll
      for (int i = 0; i < 64; i++){
        if (dv[i] <= T){
          unsigned u = __float_as_uint(dv[i]);
          u ^= (unsigned)(((int)u >> 31)) | 0x80000000u;
          skey[w][off2] = u;
          sidx[w][off2] = i*64 + l;
          off2++;
        }
      }
      unsigned long long sk = ((unsigned long long)skey[w][l] << 32) | (unsigned)sidx[w][l];
      #pragma unroll
      for (int k = 2; k <= 64; k <<= 1){
        #pragma unroll
        for (int j = k >> 1; j > 0; j >>= 1){
          unsigned long long o = __shfl_xor(sk, j);
          bool keepmin = (((l & k) == 0)) ^ ((l & j) != 0);
          unsigned long long mn = (sk < o) ? sk : o;
          unsigned long long mx = (sk < o) ? o : sk;
          sk = keepmin ? mn : mx;
        }
      }
      if (l < 32) idxout[obase + l] = (int)(unsigned)(sk & 0xFFFFFFFFull);
    } else {
      // rare exact fallback: bisection on 44-bit (key, idx) from register dv[]
      unsigned long long lo = 0, hi = (1ull << 44) - 1;
      for (int it = 0; it < 44; ++it){
        unsigned long long mid = (lo + hi) >> 1;
        unsigned midk = (unsigned)(mid >> 12);
        unsigned midi = (unsigned)(mid & 0xFFFull);
        int cc = 0;
        #pragma unroll
        for (int i = 0; i < 64; i++){
          unsigned u = __float_as_uint(dv[i]);
          u ^= (unsigned)(((int)u >> 31)) | 0x80000000u;
          unsigned n = (unsigned)(i*64 + l);
          cc += (u < midk || (u == midk && n <= midi)) ? 1 : 0;
        }
        #pragma unroll
        for (int o2 = 32; o2 > 0; o2 >>= 1) cc += __shfl_xor(cc, o2);
        if (cc >= 32) hi = mid; else lo = mid + 1;
      }
      const unsigned Ck = (unsigned)(lo >> 12);
      const unsigned Ci = (unsigned)(lo & 0xFFFull);
      int c2 = 0;
      #pragma unroll
      for (int i = 0; i < 64; i++){
        unsigned u = __float_as_uint(dv[i]);
        u ^= (unsigned)(((int)u >> 31)) | 0x80000000u;
        unsigned n = (unsigned)(i*64 + l);
        c2 += (u < Ck || (u == Ck && n <= Ci)) ? 1 : 0;
      }
      int inc2 = c2;
      #pragma unroll
      for (int off = 1; off < 64; off <<= 1){
        int t2 = __shfl_up(inc2, off);
        if (l >= off) inc2 += t2;
      }
      int off3 = inc2 - c2;
      #pragma unroll
      for (int i = 0; i < 64; i++){
        unsigned u = __float_as_uint(dv[i]);
        u ^= (unsigned)(((int)u >> 31)) | 0x80000000u;
        unsigned n = (unsigned)(i*64 + l);
        if (u < Ck || (u == Ck && n <= Ci)){
          skey[w][off3] = u;
          sidx[w][off3] = (int)n;
          off3++;
        }
      }
      if (l < 32) idxout[obase + l] = sidx[w][l];   // exactly 32, in index-sorted-by-key order
    }
  }
}

// ---- conv1: gather -> split-MFMA -> Y1 + stats. 64 rows/wave, grid 2048 ----
__global__ __launch_bounds__(256, 2) void conv1_mfma(const float* __restrict__ pts,
    const int* __restrict__ idx, const unsigned short* __restrict__ wpk,
    const float* __restrict__ bias, unsigned short* __restrict__ Yo,
    float* __restrict__ stats){
  __shared__ float sred[4][128];
  const int t = threadIdx.x, w = t>>6, l = t&63, quad = l>>4, lr = l&15;
  const int m0 = blockIdx.x*256;
  const int Rw = m0 + w*64;
  const int b = m0 >> 15;
  bf16x8 wf[4][2];
  #pragma unroll
  for (int c = 0; c < 4; c++)
    #pragma unroll
    for (int s = 0; s < 2; s++)
      wf[c][s] = *(const bf16x8*)(wpk + (((c*2+s)<<6) + l)*8);
  f32x4 acc[4][4];
  #pragma unroll
  for (int c = 0; c < 4; c++)
    #pragma unroll
    for (int rt = 0; rt < 4; rt++)
      acc[c][rt] = (f32x4){0.f,0.f,0.f,0.f};
  int ri[4];
  #pragma unroll
  for (int rt = 0; rt < 4; rt++) ri[rt] = idx[Rw + rt*16 + lr];
  #pragma unroll
  for (int s = 0; s < 2; s++){
    #pragma unroll
    for (int rt = 0; rt < 4; rt++){
      const float* pr = pts + ((size_t)(b*4096 + ri[rt]))*64;
      float4 v0 = *(const float4*)(pr + s*32 + quad*8);
      float4 v1 = *(const float4*)(pr + s*32 + quad*8 + 4);
      float xs[8] = {v0.x,v0.y,v0.z,v0.w,v1.x,v1.y,v1.z,v1.w};
      bf16x8 xh, xl;
      #pragma unroll
      for (int j = 0; j < 8; j++){ short hh, ll; split1(xs[j], hh, ll); xh[j]=hh; xl[j]=ll; }
      #pragma unroll
      for (int c = 0; c < 4; c++){
        acc[c][rt] = __builtin_amdgcn_mfma_f32_16x16x32_bf16(wf[c][s], xh, acc[c][rt], 0,0,0);
        acc[c][rt] = __builtin_amdgcn_mfma_f32_16x16x32_bf16(wf[c][s], xl, acc[c][rt], 0,0,0);
      }
    }
  }
  const int rtg0 = Rw >> 4;
  #pragma unroll
  for (int c = 0; c < 4; c++){
    float4 bq = *(const float4*)(bias + c*16 + quad*4);
    float bqa[4] = {bq.x, bq.y, bq.z, bq.w};
    float sv[4] = {0,0,0,0}, qv[4] = {0,0,0,0};
    int kb = c*2 + (quad>>1);
    int sub = (quad&1)*4;
    #pragma unroll
    for (int rt = 0; rt < 4; rt++){
      float y[4];
      #pragma unroll
      for (int r = 0; r < 4; r++){
        y[r] = acc[c][rt][r] + bqa[r];
        sv[r] += y[r];
        qv[r] += y[r]*y[r];
      }
      uint2 p;
      p.x = (unsigned)rnb(y[0]) | ((unsigned)rnb(y[1])<<16);
      p.y = (unsigned)rnb(y[2]) | ((unsigned)rnb(y[3])<<16);
      *(uint2*)(Yo + ((((rtg0+rt)*8 + kb)*16 + lr)*8 + sub)) = p;
    }
    float S = hred4_sum(sv, l);
    float Q = hred4_sum(qv, l);
    if ((l & 3) == 0){
      int ch = c*16 + quad*4 + ((l>>3)&1)*2 + ((l>>2)&1);
      sred[w][ch] = S;
      sred[w][64 + ch] = Q;
    }
  }
  __syncthreads();
  if (t < 128){
    float tot = sred[0][t]+sred[1][t]+sred[2][t]+sred[3][t];
    unsafeAtomicAdd(&stats[(blockIdx.x & 7)*512 + t], tot);
  }
}

// ---- conv2: Y1 -> affine+relu -> MFMA (no split) -> Y2 + stats. 64 rows/wave ----
__global__ __launch_bounds__(256, 2) void conv2_mfma(const unsigned short* __restrict__ Yi,
    const unsigned short* __restrict__ wpk, const float* __restrict__ bias,
    const float* __restrict__ aff, unsigned short* __restrict__ Yo,
    float* __restrict__ stats){
  __shared__ float sred[4][128];
  const int t = threadIdx.x, w = t>>6, l = t&63, quad = l>>4, lr = l&15;
  const int m0 = blockIdx.x*256;
  const int Rw = m0 + w*64;
  bf16x8 wf[4][2];
  #pragma unroll
  for (int c = 0; c < 4; c++)
    #pragma unroll
    for (int s = 0; s < 2; s++)
      wf[c][s] = *(const bf16x8*)(wpk + (((c*2+s)<<6) + l)*8);
  f32x4 acc[4][4];
  #pragma unroll
  for (int c = 0; c < 4; c++)
    #pragma unroll
    for (int rt = 0; rt < 4; rt++)
      acc[c][rt] = (f32x4){0.f,0.f,0.f,0.f};
  const int rtg0 = Rw >> 4;
  #pragma unroll
  for (int s = 0; s < 2; s++){
    float4 A0 = *(const float4*)(aff + s*32 + quad*8);
    float4 A1 = *(const float4*)(aff + s*32 + quad*8 + 4);
    float4 B0 = *(const float4*)(aff + 64 + s*32 + quad*8);
    float4 B1 = *(const float4*)(aff + 64 + s*32 + quad*8 + 4);
    float aA[8] = {A0.x,A0.y,A0.z,A0.w,A1.x,A1.y,A1.z,A1.w};
    float aB[8] = {B0.x,B0.y,B0.z,B0.w,B1.x,B1.y,B1.z,B1.w};
    #pragma unroll
    for (int rt = 0; rt < 4; rt++){
      uint4 u = *(const uint4*)(Yi + (((rtg0+rt)*8 + s*4 + quad)*16 + lr)*8);
      unsigned ua[4] = {u.x,u.y,u.z,u.w};
      bf16x8 xb;
      #pragma unroll
      for (int j = 0; j < 8; j++){
        unsigned wd = ua[j>>1];
        float yf = __uint_as_float((j&1) ? (wd & 0xFFFF0000u) : (wd << 16));
        float x = fmaxf(0.f, fmaf(yf, aA[j], aB[j]));
        xb[j] = (short)rnb(x);
      }
      #pragma unroll
      for (int c = 0; c < 4; c++)
        acc[c][rt] = __builtin_amdgcn_mfma_f32_16x16x32_bf16(wf[c][s], xb, acc[c][rt], 0,0,0);
    }
  }
  #pragma unroll
  for (int c = 0; c < 4; c++){
    float4 bq = *(const float4*)(bias + c*16 + quad*4);
    float bqa[4] = {bq.x, bq.y, bq.z, bq.w};
    float sv[4] = {0,0,0,0}, qv[4] = {0,0,0,0};
    int kb = c*2 + (quad>>1);
    int sub = (quad&1)*4;
    #pragma unroll
    for (int rt = 0; rt < 4; rt++){
      float y[4];
      #pragma unroll
      for (int r = 0; r < 4; r++){
        y[r] = acc[c][rt][r] + bqa[r];
        sv[r] += y[r];
        qv[r] += y[r]*y[r];
      }
      uint2 p;
      p.x = (unsigned)rnb(y[0]) | ((unsigned)rnb(y[1])<<16);
      p.y = (unsigned)rnb(y[2]) | ((unsigned)rnb(y[3])<<16);
      *(uint2*)(Yo + ((((rtg0+rt)*8 + kb)*16 + lr)*8 + sub)) = p;
    }
    float S = hred4_sum(sv, l);
    float Q = hred4_sum(qv, l);
    if ((l & 3) == 0){
      int ch = c*16 + quad*4 + ((l>>3)&1)*2 + ((l>>2)&1);
      sred[w][ch] = S;
      sred[w][64 + ch] = Q;
    }
  }
  __syncthreads();
  if (t < 128){
    float tot = sred[0][t]+sred[1][t]+sred[2][t]+sred[3][t];
    unsafeAtomicAdd(&stats[(blockIdx.x & 7)*512 + 128 + t], tot);
  }
}

// ---- conv3: Y2 -> affine+relu -> MFMA (no split) -> K-maxpool + stats. 32 rows/wave ----
__global__ __launch_bounds__(256, 2) void conv3_mfma(const unsigned short* __restrict__ Yi,
    const unsigned short* __restrict__ wpk, const float* __restrict__ bias,
    const float* __restrict__ aff, float* __restrict__ ymax,
    float* __restrict__ stats){
  __shared__ float sred[4][256];
  const int t = threadIdx.x, w = t>>6, l = t&63, quad = l>>4, lr = l&15;
  const int m0 = blockIdx.x*128;
  const int Rw = m0 + w*32;
  bf16x8 wf[8][2];
  #pragma unroll
  for (int c = 0; c < 8; c++)
    #pragma unroll
    for (int s = 0; s < 2; s++)
      wf[c][s] = *(const bf16x8*)(wpk + (((c*2+s)<<6) + l)*8);
  f32x4 acc[8][2];
  #pragma unroll
  for (int c = 0; c < 8; c++){
    acc[c][0] = (f32x4){0.f,0.f,0.f,0.f};
    acc[c][1] = (f32x4){0.f,0.f,0.f,0.f};
  }
  const int rtg0 = Rw >> 4;
  #pragma unroll
  for (int s = 0; s < 2; s++){
    float4 A0 = *(const float4*)(aff + s*32 + quad*8);
    float4 A1 = *(const float4*)(aff + s*32 + quad*8 + 4);
    float4 B0 = *(const float4*)(aff + 64 + s*32 + quad*8);
    float4 B1 = *(const float4*)(aff + 64 + s*32 + quad*8 + 4);
    float aA[8] = {A0.x,A0.y,A0.z,A0.w,A1.x,A1.y,A1.z,A1.w};
    float aB[8] = {B0.x,B0.y,B0.z,B0.w,B1.x,B1.y,B1.z,B1.w};
    #pragma unroll
    for (int rt = 0; rt < 2; rt++){
      uint4 u = *(const uint4*)(Yi + (((rtg0+rt)*8 + s*4 + quad)*16 + lr)*8);
      unsigned ua[4] = {u.x,u.y,u.z,u.w};
      bf16x8 xb;
      #pragma unroll
      for (int j = 0; j < 8; j++){
        unsigned wd = ua[j>>1];
        float yf = __uint_as_float((j&1) ? (wd & 0xFFFF0000u) : (wd << 16));
        float x = fmaxf(0.f, fmaf(yf, aA[j], aB[j]));
        xb[j] = (short)rnb(x);
      }
      #pragma unroll
      for (int c = 0; c < 8; c++)
        acc[c][rt] = __builtin_amdgcn_mfma_f32_16x16x32_bf16(wf[c][s], xb, acc[c][rt], 0,0,0);
    }
  }
  const int g = Rw >> 5;       // group = b*S + s (wave = one K=32 group)
  #pragma unroll
  for (int c = 0; c < 8; c++){
    float4 bq = *(const float4*)(bias + c*16 + quad*4);
    float bqa[4] = {bq.x, bq.y, bq.z, bq.w};
    float sv[4], qv[4], mv[4];
    #pragma unroll
    for (int r = 0; r < 4; r++){
      float y0 = acc[c][0][r] + bqa[r];
      float y1 = acc[c][1][r] + bqa[r];
      sv[r] = y0 + y1;
      qv[r] = y0*y0 + y1*y1;
      mv[r] = fmaxf(y0, y1);
    }
    float S = hred4_sum(sv, l);
    float Q = hred4_sum(qv, l);
    float Mx = hred4_max(mv, l);
    if ((l & 3) == 0){
      int ch = c*16 + quad*4 + ((l>>3)&1)*2 + ((l>>2)&1);
      sred[w][ch] = S;
      sred[w][128 + ch] = Q;
      ymax[(size_t)g*128 + ch] = Mx;
    }
  }
  __syncthreads();
  {
    float tot = sred[0][t]+sred[1][t]+sred[2][t]+sred[3][t];
    unsafeAtomicAdd(&stats[(blockIdx.x & 7)*512 + 256 + t], tot);
  }
}

__global__ void bnparam_kernel(const float* __restrict__ stats, const float* __restrict__ g,
                               const float* __restrict__ bt, float* __restrict__ outAS,
                               int sOff, int qOff, int C){
  int c = threadIdx.x;
  if (c >= C) return;
  const float inv = 1.f/(float)M_;
  float S = 0.f, Q = 0.f;
  #pragma unroll
  for (int r = 0; r < 8; r++){
    S += stats[r*512 + sOff + c];
    Q += stats[r*512 + qOff + c];
  }
  float mean = S * inv;
  float var  = Q * inv - mean*mean;
  float a = g[c] * rsqrtf(var + EPS_);
  outAS[c] = a;
  outAS[C + c] = bt[c] - mean*a;
}

__global__ void final_kernel(const float* __restrict__ ymax,
                             const float* __restrict__ affb, float* __restrict__ out){
  int t = blockIdx.x*256 + threadIdx.x;     // (b*S+s)*128 + o
  int o = t & 127;
  float a = affb[256 + o], s = affb[384 + o];
  // g=ones => a = rsqrt(var+eps) > 0, so max commutes with the affine+relu
  out[OUT_FEAT + t] = fmaxf(0.f, a*ymax[t] + s);
}

extern "C" void kernel_launch(void* const* d_in, const int* in_sizes, int n_in,
                              void* d_out, int out_size, void* d_ws, size_t ws_size,
                              hipStream_t stream) {
  const float* xyz = (const float*)d_in[0];
  const float* nrm = (const float*)d_in[1];
  const float* pts = (const float*)d_in[2];
  const int*   fps = (const int*)d_in[3];
  const float* w0  = (const float*)d_in[4];
  const float* b0  = (const float*)d_in[5];
  const float* g0  = (const float*)d_in[6];
  const float* bt0 = (const float*)d_in[7];
  const float* w1  = (const float*)d_in[8];
  const float* b1  = (const float*)d_in[9];
  const float* g1  = (const float*)d_in[10];
  const float* bt1 = (const float*)d_in[11];
  const float* w2  = (const float*)d_in[12];
  const float* b2  = (const float*)d_in[13];
  const float* g2  = (const float*)d_in[14];
  const float* bt2 = (const float*)d_in[15];
  float* out = (float*)d_out;

  char* ws = (char*)d_ws;
  float* stats = (float*)ws;                                  // 16 KB (8 replicas x 512 f)
  float* affb  = (float*)(ws + 16384);                        // 2 KB aff params
  int*   idxb  = (int*)(ws + 20480);                          // 2 MB
  float* ymax  = (float*)(ws + 2117632);                      // 8 MB
  unsigned short* wpack = (unsigned short*)(ws + 11554816);   // 32 KB
  unsigned short* Y1 = (unsigned short*)(ws + 18878464);      // 64 MB
  unsigned short* Y2 = (unsigned short*)(ws + 85987328);      // 64 MB (ends 153096192)

  zero_stats_kernel<<<16, 256, 0, stream>>>(stats);
  meta_kernel<<<64, 256, 0, stream>>>(xyz, nrm, fps, out);
  packw_kernel<<<64, 256, 0, stream>>>(w0, w1, w2, wpack);
  knn_kernel<<<1024, 256, 0, stream>>>(xyz, fps, idxb);
  conv1_mfma<<<2048, 256, 0, stream>>>(pts, idxb, wpack, b0, Y1, stats);
  bnparam_kernel<<<1, 64, 0, stream>>>(stats, g0, bt0, affb, 0, 64, 64);
  conv2_mfma<<<2048, 256, 0, stream>>>(Y1, wpack + 4096, b1, affb, Y2, stats);
  bnparam_kernel<<<1, 64, 0, stream>>>(stats, g1, bt1, affb + 128, 128, 192, 64);
  conv3_mfma<<<4096, 256, 0, stream>>>(Y2, wpack + 8192, b2, affb + 128, ymax, stats);
  bnparam_kernel<<<1, 128, 0, stream>>>(stats, g2, bt2, affb + 256, 256, 384, 128);
  final_kernel<<<8192, 256, 0, stream>>>(ymax, affb, out);
}

// Round 8
// 299.147 us; speedup vs baseline: 1.7131x; 1.0037x over previous
//
#include <hip/hip_runtime.h>
#include <hip/hip_bf16.h>

#define B_ 16
#define N_ 4096
#define S_ 1024
#define K_ 32
#define D_ 64
#define M_ (B_*S_*K_)            // 524288 rows
#define EPS_ 1e-5f

#define OUT_NRM  (B_*S_*3)       // 49152
#define OUT_FEAT (2*B_*S_*3)     // 98304
#define OUT_FPS  (OUT_FEAT + B_*S_*128)  // 2195456

typedef __attribute__((ext_vector_type(8))) short bf16x8;
typedef __attribute__((ext_vector_type(4))) float f32x4;

__device__ __forceinline__ unsigned short rnb(float x){
  return (unsigned short)((__float_as_uint(x) + 0x8000u) >> 16);
}
__device__ __forceinline__ void split1(float x, short& h, short& l){
  unsigned ux = __float_as_uint(x);
  unsigned uh = (ux + 0x8000u) & 0xFFFF0000u;
  h = (short)(uh >> 16);
  float lo = x - __uint_as_float(uh);
  l = (short)((__float_as_uint(lo) + 0x8000u) >> 16);
}
__device__ __forceinline__ unsigned f2key(float d){
  unsigned u = __float_as_uint(d);
  return u ^ ((unsigned)(((int)u) >> 31) | 0x80000000u);
}
__device__ __forceinline__ float key2f(unsigned u){
  unsigned v = (u & 0x80000000u) ? (u ^ 0x80000000u) : ~u;
  return __uint_as_float(v);
}

// reduce 4 values across 16 lr-lanes; lane with bits(3,2)=(b3,b2) holds total of v[2*b3+b2]
__device__ __forceinline__ float hred4_sum(const float v[4], int l){
  bool hi8 = (l & 8) != 0;
  float send0 = hi8 ? v[0] : v[2];
  float send1 = hi8 ? v[1] : v[3];
  float r0 = __shfl_xor(send0, 8);
  float r1 = __shfl_xor(send1, 8);
  float a0 = (hi8 ? v[2] : v[0]) + r0;
  float a1 = (hi8 ? v[3] : v[1]) + r1;
  bool hi4 = (l & 4) != 0;
  float send = hi4 ? a0 : a1;
  float r = __shfl_xor(send, 4);
  float a = (hi4 ? a1 : a0) + r;
  a += __shfl_xor(a, 2);
  a += __shfl_xor(a, 1);
  return a;
}
__device__ __forceinline__ float hred4_max(const float v[4], int l){
  bool hi8 = (l & 8) != 0;
  float send0 = hi8 ? v[0] : v[2];
  float send1 = hi8 ? v[1] : v[3];
  float r0 = __shfl_xor(send0, 8);
  float r1 = __shfl_xor(send1, 8);
  float a0 = fmaxf(hi8 ? v[2] : v[0], r0);
  float a1 = fmaxf(hi8 ? v[3] : v[1], r1);
  bool hi4 = (l & 4) != 0;
  float send = hi4 ? a0 : a1;
  float r = __shfl_xor(send, 4);
  float a = fmaxf(hi4 ? a1 : a0, r);
  a = fmaxf(a, __shfl_xor(a, 2));
  a = fmaxf(a, __shfl_xor(a, 1));
  return a;
}

// stats: 8 replicas x 512 floats
__global__ void zero_stats_kernel(float* __restrict__ stats){
  int t = blockIdx.x*256 + threadIdx.x;
  stats[t] = 0.f;
}

__global__ void meta_kernel(const float* __restrict__ xyz, const float* __restrict__ nrm,
                            const int* __restrict__ fps, float* __restrict__ out){
  int t = blockIdx.x*256 + threadIdx.x;
  if (t >= B_*S_) return;
  int b = t >> 10;
  int n = fps[t];
  const float* xp = xyz + ((size_t)b*N_ + n)*3;
  out[t*3+0] = xp[0]; out[t*3+1] = xp[1]; out[t*3+2] = xp[2];
  const float* pp = nrm + ((size_t)b*N_ + n)*3;
  out[OUT_NRM + t*3+0] = pp[0]; out[OUT_NRM + t*3+1] = pp[1]; out[OUT_NRM + t*3+2] = pp[2];
  out[OUT_FPS + t] = (float)n;
}

__global__ void packw_kernel(const float* __restrict__ w0, const float* __restrict__ w1,
                             const float* __restrict__ w2, unsigned short* __restrict__ dst){
  int e = blockIdx.x*256 + threadIdx.x;
  if (e >= 16384) return;
  const float* W; int base;
  if (e < 4096){ W = w0; base = 0; }
  else if (e < 8192){ W = w1; base = 4096; }
  else { W = w2; base = 8192; }
  int r = e - base;
  int frag = r >> 9;
  int lane = (r >> 3) & 63;
  int j = r & 7;
  int cht = frag >> 1, ks = frag & 1;
  int m = lane & 15, quad = lane >> 4;
  int ch = cht*16 + m, k = ks*32 + quad*8 + j;
  dst[e] = rnb(W[ch*64 + k]);
}

// ---- KNN: LDS-staged xyz; 2 queries/wave; ballot-based rank selection ----
__global__ __launch_bounds__(256, 2) void knn_kernel(const float* __restrict__ xyz,
                                                     const int* __restrict__ fps,
                                                     int* __restrict__ idxout){
  __shared__ float Lx[N_*3];            // 48 KB
  __shared__ unsigned skey[4][2][64];   // per-wave, per-query compaction
  __shared__ int      sidx[4][2][64];
  __shared__ unsigned scnt[4][2];
  const int t = threadIdx.x, w = t >> 6, l = t & 63;
  const int b = blockIdx.x >> 7;        // 128 blocks per batch
  {
    const float4* src = (const float4*)(xyz + (size_t)b*(N_*3));
    float4* dst = (float4*)Lx;
    #pragma unroll
    for (int j = 0; j < 12; j++) dst[j*256 + t] = src[j*256 + t];
  }
  __syncthreads();
  const int q0 = blockIdx.x*8 + w*2;
  const int nq0 = fps[q0], nq1 = fps[q0+1];
  const float qx0 = Lx[nq0*3], qy0 = Lx[nq0*3+1], qz0 = Lx[nq0*3+2];
  const float qx1 = Lx[nq1*3], qy1 = Lx[nq1*3+1], qz1 = Lx[nq1*3+2];
  const float qq0 = __fadd_rn(__fadd_rn(__fmul_rn(qx0,qx0), __fmul_rn(qy0,qy0)), __fmul_rn(qz0,qz0));
  const float qq1 = __fadd_rn(__fadd_rn(__fmul_rn(qx1,qx1), __fmul_rn(qy1,qy1)), __fmul_rn(qz1,qz1));
  float dv0[64], dv1[64];
  float vmin0 = 3.0e38f, vmin1 = 3.0e38f;
  #pragma unroll
  for (int i = 0; i < 64; i++){
    const float* p = &Lx[(i*64 + l)*3];
    float px = p[0], py = p[1], pz = p[2];
    float pp = __fadd_rn(__fadd_rn(__fmul_rn(px,px), __fmul_rn(py,py)), __fmul_rn(pz,pz));
    float dt0 = __fadd_rn(__fadd_rn(__fmul_rn(qx0,px), __fmul_rn(qy0,py)), __fmul_rn(qz0,pz));
    float d0  = __fsub_rn(__fadd_rn(qq0,pp), __fmul_rn(2.f,dt0));
    dv0[i] = d0; vmin0 = fminf(vmin0, d0);
    float dt1 = __fadd_rn(__fadd_rn(__fmul_rn(qx1,px), __fmul_rn(qy1,py)), __fmul_rn(qz1,pz));
    float d1  = __fsub_rn(__fadd_rn(qq1,pp), __fmul_rn(2.f,dt1));
    dv1[i] = d1; vmin1 = fminf(vmin1, d1);
  }
  // rank-31 of lane minima: fused 32-step ballot binary search in key space
  unsigned k0 = f2key(vmin0), k1 = f2key(vmin1);
  unsigned lo0 = 0, hi0 = 0xFFFFFFFFu, lo1 = 0, hi1 = 0xFFFFFFFFu;
  for (int it = 0; it < 32; ++it){
    unsigned mid0 = lo0 + ((hi0 - lo0) >> 1);
    unsigned mid1 = lo1 + ((hi1 - lo1) >> 1);
    unsigned long long m0 = __ballot(k0 <= mid0);
    unsigned long long m1 = __ballot(k1 <= mid1);
    if (__popcll(m0) > 31) hi0 = mid0; else lo0 = mid0 + 1;
    if (__popcll(m1) > 31) hi1 = mid1; else lo1 = mid1 + 1;
  }
  const float T0 = key2f(lo0), T1 = key2f(lo1);
  // init compaction buffers (same-wave LDS, in-order DS pipe)
  skey[w][0][l] = 0xFFFFFFFFu; skey[w][1][l] = 0xFFFFFFFFu;
  sidx[w][0][l] = 0xFFF;       sidx[w][1][l] = 0xFFF;
  if (l == 0){ scnt[w][0] = 0; scnt[w][1] = 0; }
  #pragma unroll
  for (int i = 0; i < 64; i++){
    int n = i*64 + l;
    float d0 = dv0[i];
    if (d0 <= T0){
      unsigned pos = atomicAdd(&scnt[w][0], 1u);
      if (pos < 64){ skey[w][0][pos] = f2key(d0); sidx[w][0][pos] = n; }
    }
    float d1 = dv1[i];
    if (d1 <= T1){
      unsigned pos = atomicAdd(&scnt[w][1], 1u);
      if (pos < 64){ skey[w][1][pos] = f2key(d1); sidx[w][1][pos] = n; }
    }
  }
  const unsigned tot0 = scnt[w][0], tot1 = scnt[w][1];   // >= 32 guaranteed

  // ---- query 0 ----
  {
    const size_t ob = (size_t)q0 * K_;
    if (tot0 <= 64){
      unsigned long long pair = ((unsigned long long)skey[w][0][l] << 12) | (unsigned)sidx[w][0][l];
      unsigned long long plo = 0, phi = (1ull << 44) - 1;
      for (int it = 0; it < 44; ++it){
        unsigned long long mid = plo + ((phi - plo) >> 1);
        unsigned long long m = __ballot(pair <= mid);
        if (__popcll(m) >= 32) phi = mid; else plo = mid + 1;
      }
      bool sel = (pair <= plo);   // exactly 32 lanes (pairs distinct)
      unsigned long long m = __ballot(sel);
      unsigned pos = __builtin_amdgcn_mbcnt_hi((unsigned)(m >> 32),
                     __builtin_amdgcn_mbcnt_lo((unsigned)m, 0u));
      if (sel) idxout[ob + pos] = (int)(pair & 0xFFFull);
    } else {
      unsigned long long lo = 0, hi = (1ull << 44) - 1;
      for (int it = 0; it < 44; ++it){
        unsigned long long mid = (lo + hi) >> 1;
        unsigned midk = (unsigned)(mid >> 12);
        unsigned midi = (unsigned)(mid & 0xFFFull);
        int cc = 0;
        #pragma unroll
        for (int i = 0; i < 64; i++){
          unsigned u = f2key(dv0[i]);
          unsigned n = (unsigned)(i*64 + l);
          cc += (u < midk || (u == midk && n <= midi)) ? 1 : 0;
        }
        #pragma unroll
        for (int o2 = 32; o2 > 0; o2 >>= 1) cc += __shfl_xor(cc, o2);
        if (cc >= 32) hi = mid; else lo = mid + 1;
      }
      const unsigned Ck = (unsigned)(lo >> 12);
      const unsigned Ci = (unsigned)(lo & 0xFFFull);
      int c2 = 0;
      #pragma unroll
      for (int i = 0; i < 64; i++){
        unsigned u = f2key(dv0[i]);
        unsigned n = (unsigned)(i*64 + l);
        c2 += (u < Ck || (u == Ck && n <= Ci)) ? 1 : 0;
      }
      int inc2 = c2;
      #pragma unroll
      for (int off = 1; off < 64; off <<= 1){
        int t2 = __shfl_up(inc2, off);
        if (l >= off) inc2 += t2;
      }
      int off3 = inc2 - c2;
      #pragma unroll
      for (int i = 0; i < 64; i++){
        unsigned u = f2key(dv0[i]);
        unsigned n = (unsigned)(i*64 + l);
        if (u < Ck || (u == Ck && n <= Ci)){
          sidx[w][0][off3] = (int)n;
          off3++;
        }
      }
      if (l < 32) idxout[ob + l] = sidx[w][0][l];
    }
  }
  // ---- query 1 ----
  {
    const size_t ob = (size_t)(q0+1) * K_;
    if (tot1 <= 64){
      unsigned long long pair = ((unsigned long long)skey[w][1][l] << 12) | (unsigned)sidx[w][1][l];
      unsigned long long plo = 0, phi = (1ull << 44) - 1;
      for (int it = 0; it < 44; ++it){
        unsigned long long mid = plo + ((phi - plo) >> 1);
        unsigned long long m = __ballot(pair <= mid);
        if (__popcll(m) >= 32) phi = mid; else plo = mid + 1;
      }
      bool sel = (pair <= plo);
      unsigned long long m = __ballot(sel);
      unsigned pos = __builtin_amdgcn_mbcnt_hi((unsigned)(m >> 32),
                     __builtin_amdgcn_mbcnt_lo((unsigned)m, 0u));
      if (sel) idxout[ob + pos] = (int)(pair & 0xFFFull);
    } else {
      unsigned long long lo = 0, hi = (1ull << 44) - 1;
      for (int it = 0; it < 44; ++it){
        unsigned long long mid = (lo + hi) >> 1;
        unsigned midk = (unsigned)(mid >> 12);
        unsigned midi = (unsigned)(mid & 0xFFFull);
        int cc = 0;
        #pragma unroll
        for (int i = 0; i < 64; i++){
          unsigned u = f2key(dv1[i]);
          unsigned n = (unsigned)(i*64 + l);
          cc += (u < midk || (u == midk && n <= midi)) ? 1 : 0;
        }
        #pragma unroll
        for (int o2 = 32; o2 > 0; o2 >>= 1) cc += __shfl_xor(cc, o2);
        if (cc >= 32) hi = mid; else lo = mid + 1;
      }
      const unsigned Ck = (unsigned)(lo >> 12);
      const unsigned Ci = (unsigned)(lo & 0xFFFull);
      int c2 = 0;
      #pragma unroll
      for (int i = 0; i < 64; i++){
        unsigned u = f2key(dv1[i]);
        unsigned n = (unsigned)(i*64 + l);
        c2 += (u < Ck || (u == Ck && n <= Ci)) ? 1 : 0;
      }
      int inc2 = c2;
      #pragma unroll
      for (int off = 1; off < 64; off <<= 1){
        int t2 = __shfl_up(inc2, off);
        if (l >= off) inc2 += t2;
      }
      int off3 = inc2 - c2;
      #pragma unroll
      for (int i = 0; i < 64; i++){
        unsigned u = f2key(dv1[i]);
        unsigned n = (unsigned)(i*64 + l);
        if (u < Ck || (u == Ck && n <= Ci)){
          sidx[w][1][off3] = (int)n;
          off3++;
        }
      }
      if (l < 32) idxout[ob + l] = sidx[w][1][l];
    }
  }
}

// ---- conv1: gather -> split-MFMA -> Y1 + stats. 64 rows/wave, grid 2048 ----
__global__ __launch_bounds__(256, 2) void conv1_mfma(const float* __restrict__ pts,
    const int* __restrict__ idx, const unsigned short* __restrict__ wpk,
    const float* __restrict__ bias, unsigned short* __restrict__ Yo,
    float* __restrict__ stats){
  __shared__ float sred[4][128];
  const int t = threadIdx.x, w = t>>6, l = t&63, quad = l>>4, lr = l&15;
  const int m0 = blockIdx.x*256;
  const int Rw = m0 + w*64;
  const int b = m0 >> 15;
  bf16x8 wf[4][2];
  #pragma unroll
  for (int c = 0; c < 4; c++)
    #pragma unroll
    for (int s = 0; s < 2; s++)
      wf[c][s] = *(const bf16x8*)(wpk + (((c*2+s)<<6) + l)*8);
  f32x4 acc[4][4];
  #pragma unroll
  for (int c = 0; c < 4; c++)
    #pragma unroll
    for (int rt = 0; rt < 4; rt++)
      acc[c][rt] = (f32x4){0.f,0.f,0.f,0.f};
  int ri[4];
  #pragma unroll
  for (int rt = 0; rt < 4; rt++) ri[rt] = idx[Rw + rt*16 + lr];
  #pragma unroll
  for (int s = 0; s < 2; s++){
    #pragma unroll
    for (int rt = 0; rt < 4; rt++){
      const float* pr = pts + ((size_t)(b*4096 + ri[rt]))*64;
      float4 v0 = *(const float4*)(pr + s*32 + quad*8);
      float4 v1 = *(const float4*)(pr + s*32 + quad*8 + 4);
      float xs[8] = {v0.x,v0.y,v0.z,v0.w,v1.x,v1.y,v1.z,v1.w};
      bf16x8 xh, xl;
      #pragma unroll
      for (int j = 0; j < 8; j++){ short hh, ll; split1(xs[j], hh, ll); xh[j]=hh; xl[j]=ll; }
      #pragma unroll
      for (int c = 0; c < 4; c++){
        acc[c][rt] = __builtin_amdgcn_mfma_f32_16x16x32_bf16(wf[c][s], xh, acc[c][rt], 0,0,0);
        acc[c][rt] = __builtin_amdgcn_mfma_f32_16x16x32_bf16(wf[c][s], xl, acc[c][rt], 0,0,0);
      }
    }
  }
  const int rtg0 = Rw >> 4;
  #pragma unroll
  for (int c = 0; c < 4; c++){
    float4 bq = *(const float4*)(bias + c*16 + quad*4);
    float bqa[4] = {bq.x, bq.y, bq.z, bq.w};
    float sv[4] = {0,0,0,0}, qv[4] = {0,0,0,0};
    int kb = c*2 + (quad>>1);
    int sub = (quad&1)*4;
    #pragma unroll
    for (int rt = 0; rt < 4; rt++){
      float y[4];
      #pragma unroll
      for (int r = 0; r < 4; r++){
        y[r] = acc[c][rt][r] + bqa[r];
        sv[r] += y[r];
        qv[r] += y[r]*y[r];
      }
      uint2 p;
      p.x = (unsigned)rnb(y[0]) | ((unsigned)rnb(y[1])<<16);
      p.y = (unsigned)rnb(y[2]) | ((unsigned)rnb(y[3])<<16);
      *(uint2*)(Yo + ((((rtg0+rt)*8 + kb)*16 + lr)*8 + sub)) = p;
    }
    float S = hred4_sum(sv, l);
    float Q = hred4_sum(qv, l);
    if ((l & 3) == 0){
      int ch = c*16 + quad*4 + ((l>>3)&1)*2 + ((l>>2)&1);
      sred[w][ch] = S;
      sred[w][64 + ch] = Q;
    }
  }
  __syncthreads();
  if (t < 128){
    float tot = sred[0][t]+sred[1][t]+sred[2][t]+sred[3][t];
    unsafeAtomicAdd(&stats[(blockIdx.x & 7)*512 + t], tot);
  }
}

// ---- conv2: Y1 -> affine+relu -> MFMA (no split) -> Y2 + stats. 64 rows/wave ----
__global__ __launch_bounds__(256, 2) void conv2_mfma(const unsigned short* __restrict__ Yi,
    const unsigned short* __restrict__ wpk, const float* __restrict__ bias,
    const float* __restrict__ aff, unsigned short* __restrict__ Yo,
    float* __restrict__ stats){
  __shared__ float sred[4][128];
  const int t = threadIdx.x, w = t>>6, l = t&63, quad = l>>4, lr = l&15;
  const int m0 = blockIdx.x*256;
  const int Rw = m0 + w*64;
  bf16x8 wf[4][2];
  #pragma unroll
  for (int c = 0; c < 4; c++)
    #pragma unroll
    for (int s = 0; s < 2; s++)
      wf[c][s] = *(const bf16x8*)(wpk + (((c*2+s)<<6) + l)*8);
  f32x4 acc[4][4];
  #pragma unroll
  for (int c = 0; c < 4; c++)
    #pragma unroll
    for (int rt = 0; rt < 4; rt++)
      acc[c][rt] = (f32x4){0.f,0.f,0.f,0.f};
  const int rtg0 = Rw >> 4;
  #pragma unroll
  for (int s = 0; s < 2; s++){
    float4 A0 = *(const float4*)(aff + s*32 + quad*8);
    float4 A1 = *(const float4*)(aff + s*32 + quad*8 + 4);
    float4 B0 = *(const float4*)(aff + 64 + s*32 + quad*8);
    float4 B1 = *(const float4*)(aff + 64 + s*32 + quad*8 + 4);
    float aA[8] = {A0.x,A0.y,A0.z,A0.w,A1.x,A1.y,A1.z,A1.w};
    float aB[8] = {B0.x,B0.y,B0.z,B0.w,B1.x,B1.y,B1.z,B1.w};
    #pragma unroll
    for (int rt = 0; rt < 4; rt++){
      uint4 u = *(const uint4*)(Yi + (((rtg0+rt)*8 + s*4 + quad)*16 + lr)*8);
      unsigned ua[4] = {u.x,u.y,u.z,u.w};
      bf16x8 xb;
      #pragma unroll
      for (int j = 0; j < 8; j++){
        unsigned wd = ua[j>>1];
        float yf = __uint_as_float((j&1) ? (wd & 0xFFFF0000u) : (wd << 16));
        float x = fmaxf(0.f, fmaf(yf, aA[j], aB[j]));
        xb[j] = (short)rnb(x);
      }
      #pragma unroll
      for (int c = 0; c < 4; c++)
        acc[c][rt] = __builtin_amdgcn_mfma_f32_16x16x32_bf16(wf[c][s], xb, acc[c][rt], 0,0,0);
    }
  }
  #pragma unroll
  for (int c = 0; c < 4; c++){
    float4 bq = *(const float4*)(bias + c*16 + quad*4);
    float bqa[4] = {bq.x, bq.y, bq.z, bq.w};
    float sv[4] = {0,0,0,0}, qv[4] = {0,0,0,0};
    int kb = c*2 + (quad>>1);
    int sub = (quad&1)*4;
    #pragma unroll
    for (int rt = 0; rt < 4; rt++){
      float y[4];
      #pragma unroll
      for (int r = 0; r < 4; r++){
        y[r] = acc[c][rt][r] + bqa[r];
        sv[r] += y[r];
        qv[r] += y[r]*y[r];
      }
      uint2 p;
      p.x = (unsigned)rnb(y[0]) | ((unsigned)rnb(y[1])<<16);
      p.y = (unsigned)rnb(y[2]) | ((unsigned)rnb(y[3])<<16);
      *(uint2*)(Yo + ((((rtg0+rt)*8 + kb)*16 + lr)*8 + sub)) = p;
    }
    float S = hred4_sum(sv, l);
    float Q = hred4_sum(qv, l);
    if ((l & 3) == 0){
      int ch = c*16 + quad*4 + ((l>>3)&1)*2 + ((l>>2)&1);
      sred[w][ch] = S;
      sred[w][64 + ch] = Q;
    }
  }
  __syncthreads();
  if (t < 128){
    float tot = sred[0][t]+sred[1][t]+sred[2][t]+sred[3][t];
    unsafeAtomicAdd(&stats[(blockIdx.x & 7)*512 + 128 + t], tot);
  }
}

// ---- conv3: Y2 -> affine+relu -> MFMA (no split) -> K-maxpool + stats. 32 rows/wave ----
__global__ __launch_bounds__(256, 2) void conv3_mfma(const unsigned short* __restrict__ Yi,
    const unsigned short* __restrict__ wpk, const float* __restrict__ bias,
    const float* __restrict__ aff, float* __restrict__ ymax,
    float* __restrict__ stats){
  __shared__ float sred[4][256];
  const int t = threadIdx.x, w = t>>6, l = t&63, quad = l>>4, lr = l&15;
  const int m0 = blockIdx.x*128;
  const int Rw = m0 + w*32;
  bf16x8 wf[8][2];
  #pragma unroll
  for (int c = 0; c < 8; c++)
    #pragma unroll
    for (int s = 0; s < 2; s++)
      wf[c][s] = *(const bf16x8*)(wpk + (((c*2+s)<<6) + l)*8);
  f32x4 acc[8][2];
  #pragma unroll
  for (int c = 0; c < 8; c++){
    acc[c][0] = (f32x4){0.f,0.f,0.f,0.f};
    acc[c][1] = (f32x4){0.f,0.f,0.f,0.f};
  }
  const int rtg0 = Rw >> 4;
  #pragma unroll
  for (int s = 0; s < 2; s++){
    float4 A0 = *(const float4*)(aff + s*32 + quad*8);
    float4 A1 = *(const float4*)(aff + s*32 + quad*8 + 4);
    float4 B0 = *(const float4*)(aff + 64 + s*32 + quad*8);
    float4 B1 = *(const float4*)(aff + 64 + s*32 + quad*8 + 4);
    float aA[8] = {A0.x,A0.y,A0.z,A0.w,A1.x,A1.y,A1.z,A1.w};
    float aB[8] = {B0.x,B0.y,B0.z,B0.w,B1.x,B1.y,B1.z,B1.w};
    #pragma unroll
    for (int rt = 0; rt < 2; rt++){
      uint4 u = *(const uint4*)(Yi + (((rtg0+rt)*8 + s*4 + quad)*16 + lr)*8);
      unsigned ua[4] = {u.x,u.y,u.z,u.w};
      bf16x8 xb;
      #pragma unroll
      for (int j = 0; j < 8; j++){
        unsigned wd = ua[j>>1];
        float yf = __uint_as_float((j&1) ? (wd & 0xFFFF0000u) : (wd << 16));
        float x = fmaxf(0.f, fmaf(yf, aA[j], aB[j]));
        xb[j] = (short)rnb(x);
      }
      #pragma unroll
      for (int c = 0; c < 8; c++)
        acc[c][rt] = __builtin_amdgcn_mfma_f32_16x16x32_bf16(wf[c][s], xb, acc[c][rt], 0,0,0);
    }
  }
  const int g = Rw >> 5;
  #pragma unroll
  for (int c = 0; c < 8; c++){
    float4 bq = *(const float4*)(bias + c*16 + quad*4);
    float bqa[4] = {bq.x, bq.y, bq.z, bq.w};
    float sv[4], qv[4], mv[4];
    #pragma unroll
    for (int r = 0; r < 4; r++){
      float y0 = acc[c][0][r] + bqa[r];
      float y1 = acc[c][1][r] + bqa[r];
      sv[r] = y0 + y1;
      qv[r] = y0*y0 + y1*y1;
      mv[r] = fmaxf(y0, y1);
    }
    float S = hred4_sum(sv, l);
    float Q = hred4_sum(qv, l);
    float Mx = hred4_max(mv, l);
    if ((l & 3) == 0){
      int ch = c*16 + quad*4 + ((l>>3)&1)*2 + ((l>>2)&1);
      sred[w][ch] = S;
      sred[w][128 + ch] = Q;
      ymax[(size_t)g*128 + ch] = Mx;
    }
  }
  __syncthreads();
  {
    float tot = sred[0][t]+sred[1][t]+sred[2][t]+sred[3][t];
    unsafeAtomicAdd(&stats[(blockIdx.x & 7)*512 + 256 + t], tot);
  }
}

__global__ void bnparam_kernel(const float* __restrict__ stats, const float* __restrict__ g,
                               const float* __restrict__ bt, float* __restrict__ outAS,
                               int sOff, int qOff, int C){
  int c = threadIdx.x;
  if (c >= C) return;
  const float inv = 1.f/(float)M_;
  float S = 0.f, Q = 0.f;
  #pragma unroll
  for (int r = 0; r < 8; r++){
    S += stats[r*512 + sOff + c];
    Q += stats[r*512 + qOff + c];
  }
  float mean = S * inv;
  float var  = Q * inv - mean*mean;
  float a = g[c] * rsqrtf(var + EPS_);
  outAS[c] = a;
  outAS[C + c] = bt[c] - mean*a;
}

__global__ void final_kernel(const float* __restrict__ ymax,
                             const float* __restrict__ affb, float* __restrict__ out){
  int t = blockIdx.x*256 + threadIdx.x;
  int o = t & 127;
  float a = affb[256 + o], s = affb[384 + o];
  out[OUT_FEAT + t] = fmaxf(0.f, a*ymax[t] + s);
}

extern "C" void kernel_launch(void* const* d_in, const int* in_sizes, int n_in,
                              void* d_out, int out_size, void* d_ws, size_t ws_size,
                              hipStream_t stream) {
  const float* xyz = (const float*)d_in[0];
  const float* nrm = (const float*)d_in[1];
  const float* pts = (const float*)d_in[2];
  const int*   fps = (const int*)d_in[3];
  const float* w0  = (const float*)d_in[4];
  const float* b0  = (const float*)d_in[5];
  const float* g0  = (const float*)d_in[6];
  const float* bt0 = (const float*)d_in[7];
  const float* w1  = (const float*)d_in[8];
  const float* b1  = (const float*)d_in[9];
  const float* g1  = (const float*)d_in[10];
  const float* bt1 = (const float*)d_in[11];
  const float* w2  = (const float*)d_in[12];
  const float* b2  = (const float*)d_in[13];
  const float* g2  = (const float*)d_in[14];
  const float* bt2 = (const float*)d_in[15];
  float* out = (float*)d_out;

  char* ws = (char*)d_ws;
  float* stats = (float*)ws;                                  // 16 KB
  float* affb  = (float*)(ws + 16384);                        // 2 KB
  int*   idxb  = (int*)(ws + 20480);                          // 2 MB
  float* ymax  = (float*)(ws + 2117632);                      // 8 MB
  unsigned short* wpack = (unsigned short*)(ws + 11554816);   // 32 KB
  unsigned short* Y1 = (unsigned short*)(ws + 18878464);      // 64 MB
  unsigned short* Y2 = (unsigned short*)(ws + 85987328);      // 64 MB

  zero_stats_kernel<<<16, 256, 0, stream>>>(stats);
  meta_kernel<<<64, 256, 0, stream>>>(xyz, nrm, fps, out);
  packw_kernel<<<64, 256, 0, stream>>>(w0, w1, w2, wpack);
  knn_kernel<<<2048, 256, 0, stream>>>(xyz, fps, idxb);
  conv1_mfma<<<2048, 256, 0, stream>>>(pts, idxb, wpack, b0, Y1, stats);
  bnparam_kernel<<<1, 64, 0, stream>>>(stats, g0, bt0, affb, 0, 64, 64);
  conv2_mfma<<<2048, 256, 0, stream>>>(Y1, wpack + 4096, b1, affb, Y2, stats);
  bnparam_kernel<<<1, 64, 0, stream>>>(stats, g1, bt1, affb + 128, 128, 192, 64);
  conv3_mfma<<<4096, 256, 0, stream>>>(Y2, wpack + 8192, b2, affb + 128, ymax, stats);
  bnparam_kernel<<<1, 128, 0, stream>>>(stats, g2, bt2, affb + 256, 256, 384, 128);
  final_kernel<<<8192, 256, 0, stream>>>(ymax, affb, out);
}